// Round 4
// baseline (115.894 us; speedup 1.0000x reference)
//
#include <hip/hip_runtime.h>

#define IMG_H 1080
#define IMG_W 1920
#define TILE_W 128
#define TILE_H 32
#define SW 134           // TILE_W + 6
#define SH 38            // TILE_H + 6
#define SP 136           // padded LDS row stride (floats); 136*4B = 16B multiple

typedef float f32x4 __attribute__((ext_vector_type(4)));

// Nonzero iff the 16-bit circular mask has 9 consecutive set bits.
__device__ __forceinline__ unsigned det9(unsigned m) {
    unsigned x = m | (m << 16);
    unsigned t = x & (x >> 1);   // run 2
    t &= t >> 2;                 // run 4
    t &= t >> 4;                 // run 8
    t &= x >> 8;                 // run 9
    return t;
}

__global__ __launch_bounds__(256, 2) void fast_score_kernel(const float* __restrict__ img,
                                                            float* __restrict__ out) {
    __shared__ float sm[SH * SP];

    const int n  = blockIdx.z;
    const int x0 = blockIdx.x * TILE_W;
    const int y0 = blockIdx.y * TILE_H;
    const int tid = threadIdx.x;

    const float* in = img + (size_t)n * (IMG_H * IMG_W);
    float* op = out + (size_t)n * (IMG_H * IMG_W);

    // ---- stage tile + halo into LDS (replicate-clamped) ----
    {
        const int lane = tid & 63;
        const int rgrp = tid >> 6;
        for (int r = rgrp; r < SH; r += 4) {
            int gy = y0 - 3 + r;
            gy = min(max(gy, 0), IMG_H - 1);
            const float* rowp = in + (size_t)gy * IMG_W;
            for (int c = lane; c < SW; c += 64) {
                int gx = x0 - 3 + c;
                gx = min(max(gx, 0), IMG_W - 1);
                sm[r * SP + c] = rowp[gx];
            }
        }
    }
    __syncthreads();

    // ---- 4x4 output patch per thread, full 10x12 register window ----
    const int cg = tid & 31;     // 32 col groups * 4 = 128 cols
    const int rg = tid >> 5;     // 8 row groups * 4 = 32 rows
    const int C = cg * 4;
    const int R = rg * 4;

    f32x4 w[10][3];              // 10 rows x 12 cols = 120 floats
#pragma unroll
    for (int j = 0; j < 10; ++j) {
        const float* sp = &sm[(R + j) * SP + C];
#pragma unroll
        for (int q = 0; q < 3; ++q) {
            w[j][q] = *(const f32x4*)(sp + 4 * q);
            asm volatile("" : "+v"(w[j][q]));   // value must materialize in VGPRs here
        }
    }
    // Hard scheduling fence: NOTHING crosses (mask 0). All 30 quads are live
    // here -> allocator must keep the whole window in registers; compute below
    // cannot interleave back up into the load sequence.
    __builtin_amdgcn_sched_barrier(0);

#define WELEM(r_, c_) (w[(r_)][(c_) >> 2][(c_) & 3])

    constexpr int DY[16] = {0, 1, 2, 3, 3, 3, 2, 1, 0, -1, -2, -3, -3, -3, -2, -1};
    constexpr int DX[16] = {-3, -3, -2, -1, 0, 1, 2, 3, 3, 3, 2, 1, 0, -1, -2, -3};

#pragma unroll
    for (int rr = 0; rr < 4; ++rr) {
        float res[4];
#pragma unroll
        for (int cc = 0; cc < 4; ++cc) {
            const float center = WELEM(rr + 3, cc + 3);
            const float hi = center + 20.0f;
            const float lo = center - 20.0f;
            unsigned dark = 0u, bright = 0u;
#pragma unroll
            for (int k = 0; k < 16; ++k) {
                const float t = WELEM(rr + 3 + DY[k], cc + 3 + DX[k]);
                dark   = (dark << 1)   + (t >= hi ? 1u : 0u);
                bright = (bright << 1) + (t <= lo ? 1u : 0u);
            }
            res[cc] = (det9(dark) | det9(bright)) ? 1.0f : 0.0f;
        }
        const int gy = y0 + R + rr;
        if (gy < IMG_H) {
            *(float4*)(op + (size_t)gy * IMG_W + (x0 + C)) =
                make_float4(res[0], res[1], res[2], res[3]);
        }
    }
}

extern "C" void kernel_launch(void* const* d_in, const int* in_sizes, int n_in,
                              void* d_out, int out_size, void* d_ws, size_t ws_size,
                              hipStream_t stream) {
    const float* img = (const float*)d_in[0];
    float* out = (float*)d_out;
    const int n_img = in_sizes[0] / (IMG_H * IMG_W);   // = 4
    dim3 grid((IMG_W + TILE_W - 1) / TILE_W,           // 15
              (IMG_H + TILE_H - 1) / TILE_H,           // 34
              n_img);
    fast_score_kernel<<<grid, 256, 0, stream>>>(img, out);
}

// Round 5
// 110.898 us; speedup vs baseline: 1.0451x; 1.0451x over previous
//
#include <hip/hip_runtime.h>

#define IMG_H 1080
#define IMG_W 1920
#define TILE_W 64
#define TILE_H 4
#define SW 70            // TILE_W + 6
#define SH 10            // TILE_H + 6
#define SP 72            // padded LDS row stride (floats)

// Nonzero iff the 16-bit circular mask has 9 consecutive set bits.
// (Equivalent to the reference's 24-bit buffer window test.)
__device__ __forceinline__ unsigned det9(unsigned m) {
    unsigned x = m | (m << 16);
    unsigned t = x & (x >> 1);   // run 2
    t &= t >> 2;                 // run 4
    t &= t >> 4;                 // run 8
    t &= x >> 8;                 // run 9
    return t;
}

__global__ __launch_bounds__(256) void fast_score_kernel(const float* __restrict__ img,
                                                         float* __restrict__ out) {
    __shared__ float sm[SH * SP];

    const int n  = blockIdx.z;
    const int x0 = blockIdx.x * TILE_W;
    const int y0 = blockIdx.y * TILE_H;
    const int tid = threadIdx.x;

    const float* in = img + (size_t)n * (IMG_H * IMG_W);
    float* op = out + (size_t)n * (IMG_H * IMG_W);

    // ---- stage 10x70 tile+halo into LDS (replicate-clamped), 700 elems ----
    for (int i = tid; i < SH * SW; i += 256) {
        const int r = i / SW;
        const int c = i - r * SW;
        int gy = min(max(y0 - 3 + r, 0), IMG_H - 1);
        int gx = min(max(x0 - 3 + c, 0), IMG_W - 1);
        sm[r * SP + c] = in[(size_t)gy * IMG_W + gx];
    }
    __syncthreads();

    // ---- 1 px per thread ----
    const int tx = tid & 63;          // 0..63
    const int ty = tid >> 6;          // 0..3
    const float* base = &sm[(ty + 3) * SP + (tx + 3)];   // center address

    constexpr int DY[16] = {0, 1, 2, 3, 3, 3, 2, 1, 0, -1, -2, -3, -3, -3, -2, -1};
    constexpr int DX[16] = {-3, -3, -2, -1, 0, 1, 2, 3, 3, 3, 2, 1, 0, -1, -2, -3};

    const float center = base[0];
    float t[16];
#pragma unroll
    for (int k = 0; k < 16; ++k) {
        t[k] = base[DY[k] * SP + DX[k]];
    }

    const float hi = center + 20.0f;
    const float lo = center - 20.0f;
    unsigned dark = 0u, bright = 0u;
#pragma unroll
    for (int k = 0; k < 16; ++k) {
        dark   |= (t[k] >= hi ? 1u : 0u) << k;
        bright |= (t[k] <= lo ? 1u : 0u) << k;
    }

    const float res = (det9(dark) | det9(bright)) ? 1.0f : 0.0f;
    op[(size_t)(y0 + ty) * IMG_W + (x0 + tx)] = res;
}

extern "C" void kernel_launch(void* const* d_in, const int* in_sizes, int n_in,
                              void* d_out, int out_size, void* d_ws, size_t ws_size,
                              hipStream_t stream) {
    const float* img = (const float*)d_in[0];
    float* out = (float*)d_out;
    const int n_img = in_sizes[0] / (IMG_H * IMG_W);   // = 4
    dim3 grid(IMG_W / TILE_W,    // 30
              IMG_H / TILE_H,    // 270
              n_img);            // 4  -> 32400 blocks
    fast_score_kernel<<<grid, 256, 0, stream>>>(img, out);
}

// Round 6
// 107.252 us; speedup vs baseline: 1.0806x; 1.0340x over previous
//
#include <hip/hip_runtime.h>

#define IMG_H 1080
#define IMG_W 1920
#define TILE_W 64
#define TILE_H 16
#define SW 70            // TILE_W + 6
#define SH 22            // TILE_H + 6
#define SP 72            // LDS row stride (floats)

// Nonzero iff the 16-bit circular mask has 9 consecutive set bits.
// (Bit order may be reversed vs reference; run-of-9 existence is
//  rotation/reflection invariant. Validated absmax=0 rounds 1-5.)
__device__ __forceinline__ unsigned det9(unsigned m) {
    unsigned x = m | (m << 16);
    unsigned t = x & (x >> 1);   // run 2
    t &= t >> 2;                 // run 4
    t &= t >> 4;                 // run 8
    t &= x >> 8;                 // run 9
    return t;
}

__global__ __launch_bounds__(256) void fast_score_kernel(const float* __restrict__ img,
                                                         float* __restrict__ out) {
    __shared__ float sm[SH * SP];

    const int n  = blockIdx.z;
    const int x0 = blockIdx.x * TILE_W;
    const int y0 = blockIdx.y * TILE_H;
    const int tid = threadIdx.x;

    const float* in = img + (size_t)n * (IMG_H * IMG_W);
    float* op = out + (size_t)n * (IMG_H * IMG_W);

    // ---- stage 22x70 tile+halo into LDS (replicate-clamped), 1540 elems ----
    for (int i = tid; i < SH * SW; i += 256) {
        const int r = i / SW;
        const int c = i - r * SW;
        int gy = min(max(y0 - 3 + r, 0), IMG_H - 1);
        int gx = min(max(x0 - 3 + c, 0), IMG_W - 1);
        sm[r * SP + c] = in[(size_t)gy * IMG_W + gx];
    }
    __syncthreads();

    // ---- 4 px per thread: same column, 4 consecutive rows ----
    const int tx  = tid & 63;          // 0..63
    const int ty0 = (tid >> 6) * 4;    // 0,4,8,12

    constexpr int DY[16] = {0, 1, 2, 3, 3, 3, 2, 1, 0, -1, -2, -3, -3, -3, -2, -1};
    constexpr int DX[16] = {-3, -3, -2, -1, 0, 1, 2, 3, 3, 3, 2, 1, 0, -1, -2, -3};

    const float* base0 = &sm[(ty0 + 3) * SP + (tx + 3)];

#pragma unroll
    for (int p = 0; p < 4; ++p) {
        const float* base = base0 + p * SP;   // all tap offsets static -> ds_read imm offsets
        const float center = base[0];
        float t[16];
#pragma unroll
        for (int k = 0; k < 16; ++k) {
            t[k] = base[DY[k] * SP + DX[k]];
        }
        const float hi = center + 20.0f;
        const float lo = center - 20.0f;
        unsigned dark = 0u, bright = 0u;
#pragma unroll
        for (int k = 0; k < 16; ++k) {
            dark   = (dark << 1)   + (t[k] >= hi ? 1u : 0u);   // cmp + addc: 2 inst/bit
            bright = (bright << 1) + (t[k] <= lo ? 1u : 0u);
        }
        const float res = (det9(dark) | det9(bright)) ? 1.0f : 0.0f;
        const int gy = y0 + ty0 + p;
        if (gy < IMG_H) {
            op[(size_t)gy * IMG_W + (x0 + tx)] = res;
        }
    }
}

extern "C" void kernel_launch(void* const* d_in, const int* in_sizes, int n_in,
                              void* d_out, int out_size, void* d_ws, size_t ws_size,
                              hipStream_t stream) {
    const float* img = (const float*)d_in[0];
    float* out = (float*)d_out;
    const int n_img = in_sizes[0] / (IMG_H * IMG_W);   // = 4
    dim3 grid(IMG_W / TILE_W,                 // 30
              (IMG_H + TILE_H - 1) / TILE_H,  // 68 (last block row-guarded)
              n_img);                         // 4  -> 8160 blocks
    fast_score_kernel<<<grid, 256, 0, stream>>>(img, out);
}

// Round 7
// 103.792 us; speedup vs baseline: 1.1166x; 1.0333x over previous
//
#include <hip/hip_runtime.h>

#define IMG_H 1080
#define IMG_W 1920
#define SY 16           // rows per thread strip

// Nonzero iff the 16-bit circular mask has 9 consecutive set bits.
__device__ __forceinline__ unsigned det9(unsigned m) {
    unsigned x = m | (m << 16);
    unsigned t = x & (x >> 1);   // run 2
    t &= t >> 2;                 // run 4
    t &= t >> 4;                 // run 8
    t &= x >> 8;                 // run 9
    return t;
}

__global__ __launch_bounds__(256) void fast_score_kernel(const float* __restrict__ img,
                                                         float* __restrict__ out) {
    const int n  = blockIdx.z;
    const int gx = blockIdx.x * 256 + threadIdx.x;   // 0..2047 (tail clamped)
    const int y0 = blockIdx.y * SY;

    const float* base = img + (size_t)n * (IMG_H * IMG_W);
    float* ob = out + (size_t)n * (IMG_H * IMG_W);

    // clamped column indices for dx = -3..3
    int c[7];
#pragma unroll
    for (int d = 0; d < 7; ++d) c[d] = min(max(gx + d - 3, 0), IMG_W - 1);

#define ROWP(r) (base + (size_t)min(max((r), 0), IMG_H - 1) * IMG_W)

    // Rolling per-column register buffers for pixel y:
    //  L   (dx=-3): rows y-1..y+1      Rr  (dx=+3): rows y-1..y+1
    //  a2m (dx=-2): rows y-2..y+2      a2p (dx=+2): rows y-2..y+2
    //  a1m (dx=-1): rows y-3..y+3      a1p (dx=+1): rows y-3..y+3
    //  a0  (dx= 0): rows y-3..y+3  (center = a0[3])
    float L[3], Rr[3], a2m[5], a2p[5], a1m[7], a1p[7], a0[7];
#pragma unroll
    for (int i = 0; i < 3; ++i) { L[i]   = ROWP(y0 - 1 + i)[c[0]]; Rr[i]  = ROWP(y0 - 1 + i)[c[6]]; }
#pragma unroll
    for (int i = 0; i < 5; ++i) { a2m[i] = ROWP(y0 - 2 + i)[c[1]]; a2p[i] = ROWP(y0 - 2 + i)[c[5]]; }
#pragma unroll
    for (int i = 0; i < 7; ++i) {
        a1m[i] = ROWP(y0 - 3 + i)[c[2]];
        a0[i]  = ROWP(y0 - 3 + i)[c[3]];
        a1p[i] = ROWP(y0 - 3 + i)[c[4]];
    }

#pragma unroll
    for (int j = 0; j < SY; ++j) {
        const int y = y0 + j;

        // prefetch the 7 values pixel y+1 will need (issued before compute -> slack)
        const float nl  = ROWP(y + 2)[c[0]];
        const float nr  = ROWP(y + 2)[c[6]];
        const float n2m = ROWP(y + 3)[c[1]];
        const float n2p = ROWP(y + 3)[c[5]];
        const float n1m = ROWP(y + 4)[c[2]];
        const float n0c = ROWP(y + 4)[c[3]];
        const float n1p = ROWP(y + 4)[c[4]];

        // circle taps in circular order k=0..15 (CIRCLE_OFFSETS order)
        const float center = a0[3];
        const float hi = center + 20.0f;
        const float lo = center - 20.0f;
        const float t[16] = {L[1], L[2], a2m[4], a1m[6], a0[6], a1p[6], a2p[4], Rr[2],
                             Rr[1], Rr[0], a2p[0], a1p[0], a0[0], a1m[0], a2m[0], L[0]};
        unsigned dark = 0u, bright = 0u;
#pragma unroll
        for (int k = 0; k < 16; ++k) {
            dark   = (dark << 1)   + (t[k] >= hi ? 1u : 0u);
            bright = (bright << 1) + (t[k] <= lo ? 1u : 0u);
        }
        const float res = (det9(dark) | det9(bright)) ? 1.0f : 0.0f;
        if (gx < IMG_W && y < IMG_H) ob[(size_t)y * IMG_W + gx] = res;

        // rotate buffers (pure register renaming after unroll)
        L[0] = L[1];  L[1] = L[2];  L[2] = nl;
        Rr[0] = Rr[1]; Rr[1] = Rr[2]; Rr[2] = nr;
        a2m[0] = a2m[1]; a2m[1] = a2m[2]; a2m[2] = a2m[3]; a2m[3] = a2m[4]; a2m[4] = n2m;
        a2p[0] = a2p[1]; a2p[1] = a2p[2]; a2p[2] = a2p[3]; a2p[3] = a2p[4]; a2p[4] = n2p;
        a1m[0] = a1m[1]; a1m[1] = a1m[2]; a1m[2] = a1m[3]; a1m[3] = a1m[4]; a1m[4] = a1m[5]; a1m[5] = a1m[6]; a1m[6] = n1m;
        a1p[0] = a1p[1]; a1p[1] = a1p[2]; a1p[2] = a1p[3]; a1p[3] = a1p[4]; a1p[4] = a1p[5]; a1p[5] = a1p[6]; a1p[6] = n1p;
        a0[0]  = a0[1];  a0[1]  = a0[2];  a0[2]  = a0[3];  a0[3]  = a0[4];  a0[4]  = a0[5];  a0[5]  = a0[6];  a0[6]  = n0c;
    }
#undef ROWP
}

extern "C" void kernel_launch(void* const* d_in, const int* in_sizes, int n_in,
                              void* d_out, int out_size, void* d_ws, size_t ws_size,
                              hipStream_t stream) {
    const float* img = (const float*)d_in[0];
    float* out = (float*)d_out;
    const int n_img = in_sizes[0] / (IMG_H * IMG_W);   // = 4
    dim3 grid((IMG_W + 255) / 256,            // 8
              (IMG_H + SY - 1) / SY,          // 68 (last strip store-guarded)
              n_img);                         // 4  -> 2176 blocks
    fast_score_kernel<<<grid, 256, 0, stream>>>(img, out);
}

// Round 8
// 102.853 us; speedup vs baseline: 1.1268x; 1.0091x over previous
//
#include <hip/hip_runtime.h>

#define IMG_H 1080
#define IMG_W 1920
#define TILE_W 32
#define TILE_H 32
#define SW 38            // TILE_W + 6
#define SH 38            // TILE_H + 6
#define SP 40            // LDS row stride (dwords): small so ds_read2 offsets fit in 8 bits

// Nonzero iff the 16-bit circular mask has 9 consecutive set bits.
// (Validated vs reference, absmax=0, rounds 1-7.)
__device__ __forceinline__ unsigned det9(unsigned m) {
    unsigned x = m | (m << 16);
    unsigned t = x & (x >> 1);   // run 2
    t &= t >> 2;                 // run 4
    t &= t >> 4;                 // run 8
    t &= x >> 8;                 // run 9
    return t;
}

// m = (m << 1) | (val >= thr)  in exactly 2 VALU: v_cmp + v_addc (m+m+carry).
// Separate SGPR carry pair per chain so dark/bright interleave freely.
#define STEP_GE(m, sc, val, thr)                                          \
    asm("v_cmp_ge_f32 %1, %2, %3\n\tv_addc_co_u32 %0, %1, %0, %0, %1"     \
        : "+v"(m), "=s"(sc) : "v"(val), "v"(thr))
#define STEP_LE(m, sc, val, thr)                                          \
    asm("v_cmp_le_f32 %1, %2, %3\n\tv_addc_co_u32 %0, %1, %0, %0, %1"     \
        : "+v"(m), "=s"(sc) : "v"(val), "v"(thr))

__global__ __launch_bounds__(256) void fast_score_kernel(const float* __restrict__ img,
                                                         float* __restrict__ out) {
    __shared__ float sm[SH * SP];

    const int n  = blockIdx.z;
    const int x0 = blockIdx.x * TILE_W;
    const int y0 = blockIdx.y * TILE_H;
    const int tid = threadIdx.x;

    const float* in = img + (size_t)n * (IMG_H * IMG_W);
    float* op = out + (size_t)n * (IMG_H * IMG_W);

    // ---- stage 38x38 tile+halo into LDS (replicate-clamped), 1444 elems ----
    for (int i = tid; i < SH * SW; i += 256) {
        const int r = i / SW;
        const int c = i - r * SW;
        int gy = min(max(y0 - 3 + r, 0), IMG_H - 1);
        int gx = min(max(x0 - 3 + c, 0), IMG_W - 1);
        sm[r * SP + c] = in[(size_t)gy * IMG_W + gx];
    }
    __syncthreads();

    // ---- 4 px per thread: one column, 4 consecutive rows ----
    const int tx  = tid & 31;          // 0..31
    const int ty0 = (tid >> 5) * 4;    // 0,4,...,28

    constexpr int DY[16] = {0, 1, 2, 3, 3, 3, 2, 1, 0, -1, -2, -3, -3, -3, -2, -1};
    constexpr int DX[16] = {-3, -3, -2, -1, 0, 1, 2, 3, 3, 3, 2, 1, 0, -1, -2, -3};

#pragma unroll
    for (int p = 0; p < 4; ++p) {
        // per-pixel base: all 17 offsets are static immediates in [0, 246] dwords
        const float* base = &sm[(ty0 + 3 + p) * SP + (tx + 3)];
        const float center = base[0];
        float t[16];
#pragma unroll
        for (int k = 0; k < 16; ++k) {
            t[k] = base[DY[k] * SP + DX[k]];   // GVN dedups taps shared across p
        }
        const float hi = center + 20.0f;
        const float lo = center - 20.0f;
        unsigned dark = 0u, bright = 0u;
        unsigned long long sc0, sc1;
#pragma unroll
        for (int k = 0; k < 16; ++k) {         // circle order preserved (validated)
            STEP_GE(dark,   sc0, t[k], hi);
            STEP_LE(bright, sc1, t[k], lo);
        }
        const float res = (det9(dark) | det9(bright)) ? 1.0f : 0.0f;
        const int gy = y0 + ty0 + p;
        if (gy < IMG_H) {
            op[(size_t)gy * IMG_W + (x0 + tx)] = res;
        }
    }
}

extern "C" void kernel_launch(void* const* d_in, const int* in_sizes, int n_in,
                              void* d_out, int out_size, void* d_ws, size_t ws_size,
                              hipStream_t stream) {
    const float* img = (const float*)d_in[0];
    float* out = (float*)d_out;
    const int n_img = in_sizes[0] / (IMG_H * IMG_W);   // = 4
    dim3 grid(IMG_W / TILE_W,                 // 60
              (IMG_H + TILE_H - 1) / TILE_H,  // 34 (last row-guarded)
              n_img);                         // 4  -> 8160 blocks
    fast_score_kernel<<<grid, 256, 0, stream>>>(img, out);
}